// Round 15
// baseline (796.012 us; speedup 1.0000x reference)
//
#include <hip/hip_runtime.h>
#include <hip/hip_bf16.h>

typedef __hip_bfloat16 bft;
typedef __attribute__((ext_vector_type(8))) short bf16x8;
typedef __attribute__((ext_vector_type(4))) float f32x4;

#define BLK 256
static constexpr int Cc = 192;     // channels
static constexpr int L  = 192;     // H = W
static constexpr int S  = 36864;   // L*L
static constexpr int Bn = 2;       // batch
static constexpr int HID = 510;    // int(192*2.66)
static constexpr int CH = 64;      // FFN chunk height (image rows)
static constexpr int FTR = (CH + 2) * L;   // 12672 fT rows (with halo)
static constexpr int GTR = CH * L;         // 12288 gT rows
static constexpr double PI_D = 3.141592653589793238462643383279502884;

__device__ __forceinline__ float ldf(const float* p) { return *p; }
__device__ __forceinline__ float ldf(const bft* p)   { return __bfloat162float(*p); }
__device__ __forceinline__ void  stf(float* p, float v) { *p = v; }
__device__ __forceinline__ void  stf(bft* p, float v)   { *p = __float2bfloat16(v); }
__device__ __forceinline__ unsigned short f2bfu(float f) {
    bft h = __float2bfloat16(f);
    return *reinterpret_cast<const unsigned short*>(&h);
}
__device__ __forceinline__ unsigned short bfu(const bft* p) {
    return *reinterpret_cast<const unsigned short*>(p);
}
__device__ __forceinline__ float bu2f(unsigned short u) {
    unsigned int x = (unsigned int)u << 16;
    return __uint_as_float(x);
}
__device__ __forceinline__ bf16x8 ld8(const unsigned short* p) {   // 4B-aligned
    union { unsigned int u[4]; bf16x8 v; } t;
    const unsigned int* q = reinterpret_cast<const unsigned int*>(p);
    t.u[0] = q[0]; t.u[1] = q[1]; t.u[2] = q[2]; t.u[3] = q[3];
    return t.v;
}

// ---------------- DCT matrix init -> bf16 direct + transposed ----------------
__global__ __launch_bounds__(BLK) void k_dct_init(bft* __restrict__ dctb,
                                                  bft* __restrict__ dctTb) {
    int idx = blockIdx.x * BLK + threadIdx.x;
    if (idx >= L * L) return;
    int p = idx / L, h = idx - p * L;
    double v = (p == 0) ? sqrt(1.0 / L)
                        : cos(PI_D * p * (2 * h + 1) / (2.0 * L)) * sqrt(2.0 / L);
    bft bv = __float2bfloat16((float)v);
    dctb[p * L + h] = bv;
    dctTb[h * L + p] = bv;
}

// ---------------- fp32 weight -> bf16 with zero pad --------------------------
__global__ __launch_bounds__(BLK) void k_cvt(const float* __restrict__ src,
                                             bft* __restrict__ dst,
                                             int Mr, int Kr, int Kp) {
    int idx = blockIdx.x * BLK + threadIdx.x;
    int m = idx / Kp, k = idx - m * Kp;
    float v = (m < Mr && k < Kr) ? src[(size_t)m * Kr + k] : 0.f;
    dst[idx] = __float2bfloat16(v);
}

// ---------------- w_in -> bf16, rows remapped: f1 at 0..509, f2 at 512..1021 -
__global__ __launch_bounds__(BLK) void k_cvt_ffn(const float* __restrict__ src,
                                                 bft* __restrict__ dst) {
    int idx = blockIdx.x * BLK + threadIdx.x;   // [0, 1024*192)
    int m = idx / Cc, k = idx - m * Cc;
    float v = 0.f;
    if (m < 510) v = src[(size_t)m * Cc + k];
    else if (m >= 512 && m < 1022) v = src[(size_t)(m - 2) * Cc + k];
    dst[idx] = __float2bfloat16(v);
}

// ---------------- LayerNorm, 8 lanes/pixel, NCHW out + bf16 x-copy -----------
__global__ __launch_bounds__(BLK) void k_ln8(const float* __restrict__ x,
                                             const float* __restrict__ w,
                                             const float* __restrict__ b,
                                             bft* __restrict__ out,
                                             bft* __restrict__ xc,
                                             long zI, long zO) {
    int t = blockIdx.x * BLK + threadIdx.x;
    int s = t >> 3, u = t & 7;
    const float* xp = x + (size_t)blockIdx.y * zI + s;
    bft* op = out + (size_t)blockIdx.y * zO;
    bft* xp2 = xc + (size_t)blockIdx.y * zO;
    float vals[24];
    float sum = 0.f, sq = 0.f;
#pragma unroll
    for (int j = 0; j < 24; ++j) {
        vals[j] = xp[(size_t)(u * 24 + j) * S];
        sum += vals[j]; sq += vals[j] * vals[j];
    }
#pragma unroll
    for (int m = 1; m < 8; m <<= 1) {
        sum += __shfl_xor(sum, m);
        sq  += __shfl_xor(sq, m);
    }
    float mu = sum * (1.f / Cc);
    float var = sq * (1.f / Cc) - mu * mu;
    float r = rsqrtf(var + 1e-5f);
#pragma unroll
    for (int j = 0; j < 24; ++j) {
        int c = u * 24 + j;
        stf(op + (size_t)c * S + s, (vals[j] - mu) * r * w[c] + b[c]);
        stf(xp2 + (size_t)c * S + s, vals[j]);
    }
}

// ---------------- LayerNorm, transposed out z^T [s][c] (single-read) ---------
template <typename TI>
__global__ __launch_bounds__(BLK) void k_lnT8(const TI* __restrict__ x,
                                              const float* __restrict__ w,
                                              const float* __restrict__ b,
                                              bft* __restrict__ out,
                                              long zI, long zO) {
    int t = blockIdx.x * BLK + threadIdx.x;
    int s = t >> 3, u = t & 7;
    const TI* xp = x + (size_t)blockIdx.y * zI + s;
    float vals[24];
    float sum = 0.f, sq = 0.f;
#pragma unroll
    for (int j = 0; j < 24; ++j) {
        vals[j] = ldf(xp + (size_t)(u * 24 + j) * S);
        sum += vals[j]; sq += vals[j] * vals[j];
    }
#pragma unroll
    for (int m = 1; m < 8; m <<= 1) {
        sum += __shfl_xor(sum, m);
        sq  += __shfl_xor(sq, m);
    }
    float mu = sum * (1.f / Cc);
    float var = sq * (1.f / Cc) - mu * mu;
    float r = rsqrtf(var + 1e-5f);
    bft* op = out + (size_t)blockIdx.y * zO + (size_t)s * Cc + u * 24;
#pragma unroll
    for (int q = 0; q < 3; ++q) {
        unsigned short v8[8];
#pragma unroll
        for (int jj = 0; jj < 8; ++jj) {
            int c = u * 24 + q * 8 + jj;
            v8[jj] = f2bfu((vals[q * 8 + jj] - mu) * r * w[c] + b[c]);
        }
        *reinterpret_cast<uint4*>(op + q * 8) = *reinterpret_cast<uint4*>(v8);
    }
}

// ---------------- transpose [Cc][S] -> [S][Cc] (batched via grid.z) ----------
__global__ __launch_bounds__(BLK) void k_tr(const bft* __restrict__ in,
                                            bft* __restrict__ out, long z) {
    __shared__ unsigned short t[32][72];
    const int tid = threadIdx.x;
    const int s0 = blockIdx.x * 64, c0 = blockIdx.y * 32;
    const bft* ip = in + (size_t)blockIdx.z * z;
    bft* op = out + (size_t)blockIdx.z * z;
    {
        int c = tid >> 3, sc = (tid & 7) * 8;
        *reinterpret_cast<uint4*>(&t[c][sc]) =
            *reinterpret_cast<const uint4*>(ip + (size_t)(c0 + c) * S + s0 + sc);
    }
    __syncthreads();
    {
        int s = tid >> 2, cc = (tid & 3) * 8;
        unsigned short v[8];
#pragma unroll
        for (int q = 0; q < 8; ++q) v[q] = t[cc + q][s];
        *reinterpret_cast<uint4*>(op + (size_t)(s0 + s) * Cc + c0 + cc) =
            *reinterpret_cast<uint4*>(v);
    }
}

// ---------------- window-tiled-transposed [s*][Cc] -> NCHW spatial -----------
// block: one spatial row hh x 96 channels; reads projT rows, writes full rows
__global__ __launch_bounds__(BLK) void k_w2s(const bft* __restrict__ src,
                                             bft* __restrict__ dst,
                                             long zI, long zO) {
    __shared__ unsigned short t[192][100];
    const int tid = threadIdx.x;
    const int hh = blockIdx.x;             // 0..191 spatial row
    const int ch0 = blockIdx.y * 96;       // channel half
    const int bz = blockIdx.z;
    const int h1 = hh >> 3, ii = hh & 7;
    const bft* ip = src + (size_t)bz * zI;
    // stage 192 projT row-halves (rows: w1*8 + jj)
    for (int id = tid; id < 192 * 12; id += BLK) {
        int r = id / 12, q = id - r * 12;
        int w1 = r >> 3, jj = r & 7;
        int s = (h1 * 24 + w1) * 64 + ii * 8 + jj;
        *reinterpret_cast<uint4*>(&t[r][q * 8]) =
            *reinterpret_cast<const uint4*>(ip + (size_t)s * Cc + ch0 + q * 8);
    }
    __syncthreads();
    // write: 96 channels x 192 px (full 384B rows)
    bft* op = dst + (size_t)bz * zO;
    for (int id = tid; id < 96 * 24; id += BLK) {
        int c = id / 24, q = id - c * 24;
        unsigned short v[8];
#pragma unroll
        for (int e = 0; e < 8; ++e) v[e] = t[q * 8 + e][c];
        *reinterpret_cast<uint4*>(op + (size_t)(ch0 + c) * S + (size_t)hh * L + q * 8) =
            *reinterpret_cast<uint4*>(v);
    }
}

// =============================================================================
// Unified MFMA bf16 GEMM. Block = (WR*FM*16) x (WC*FN*16), 4 waves (WR x WC).
//   BMODE: 2 = row-major [n][k]; 4 = row-major with row-range mask [rlo,rhi)
//   OMODE: 0 = linear; 2 = window-tiled -> spatial; 3 = transposed LDS-restaged
//   BIASN: bias indexed by n (else by m)
// =============================================================================
template <int WR, int WC, int FM, int FN, int KSTEP, int BMODE, int OMODE,
          bool HASBIAS, bool BIASN, bool HASRES, typename OutT, typename ResT>
__global__ __launch_bounds__(256) void k_mm(
    const bft* __restrict__ A, int strideA, int Mreal, long zA,
    const bft* __restrict__ B, int strideB, long zB,
    OutT* __restrict__ Out, int strideO, long zO,
    const float* __restrict__ bias,
    const ResT* __restrict__ Res, long zR,
    int K, int rlo, int rhi) {
    constexpr int BM = WR * FM * 16, BN = WC * FN * 16;
    constexpr int AV = KSTEP / 8;
    __shared__ unsigned short lds[(BM + BN) * (KSTEP + 8)];
    unsigned short (*Al)[KSTEP + 8] =
        reinterpret_cast<unsigned short(*)[KSTEP + 8]>(lds);
    unsigned short (*Bl)[KSTEP + 8] =
        reinterpret_cast<unsigned short(*)[KSTEP + 8]>(lds + BM * (KSTEP + 8));
    const int tid = threadIdx.x;
    const int n0 = blockIdx.x * BN, m0 = blockIdx.y * BM, bz = blockIdx.z;
    const int lane = tid & 63, wv = tid >> 6;
    const int wr = wv / WC, wc = wv % WC;
    const int l15 = lane & 15, l4 = lane >> 4;
    f32x4 acc[FM][FN] = {};

    const bft* Ab = A + (size_t)bz * zA;
    const bft* Bb = B + (size_t)bz * zB;

    for (int k0 = 0; k0 < K; k0 += KSTEP) {
        for (int id = tid; id < BM * AV; id += 256) {
            int row = id / AV, kc = (id % AV) * 8;
            int gm = m0 + row; if (gm >= Mreal) gm = Mreal - 1;
            *reinterpret_cast<uint4*>(&Al[row][kc]) =
                *reinterpret_cast<const uint4*>(Ab + (size_t)gm * strideA + k0 + kc);
        }
        for (int id = tid; id < BN * AV; id += 256) {
            int row = id / AV, kc = (id % AV) * 8;
            int gn = n0 + row;
            uint4 val;
            if constexpr (BMODE == 2) {
                val = *reinterpret_cast<const uint4*>(
                    Bb + (size_t)gn * strideB + k0 + kc);
            } else {  // BMODE 4: masked row range
                if (gn >= rlo && gn < rhi)
                    val = *reinterpret_cast<const uint4*>(
                        Bb + (size_t)gn * strideB + k0 + kc);
                else
                    val = make_uint4(0, 0, 0, 0);
            }
            *reinterpret_cast<uint4*>(&Bl[row][kc]) = val;
        }
        __syncthreads();
#pragma unroll
        for (int kk = 0; kk < KSTEP / 32; ++kk) {
            bf16x8 af[FM], bf[FN];
#pragma unroll
            for (int i = 0; i < FM; ++i)
                af[i] = *reinterpret_cast<const bf16x8*>(
                    &Al[wr * FM * 16 + i * 16 + l15][kk * 32 + l4 * 8]);
#pragma unroll
            for (int j = 0; j < FN; ++j)
                bf[j] = *reinterpret_cast<const bf16x8*>(
                    &Bl[wc * FN * 16 + j * 16 + l15][kk * 32 + l4 * 8]);
#pragma unroll
            for (int i = 0; i < FM; ++i)
#pragma unroll
                for (int j = 0; j < FN; ++j)
                    acc[i][j] = __builtin_amdgcn_mfma_f32_16x16x32_bf16(
                        af[i], bf[j], acc[i][j], 0, 0, 0);
        }
        __syncthreads();
    }
    if constexpr (OMODE == 3) {
        constexpr int OST = BM + 8;
        unsigned short* Ol = lds;
#pragma unroll
        for (int i = 0; i < FM; ++i) {
            int mB = wr * FM * 16 + i * 16 + l4 * 4;
#pragma unroll
            for (int j = 0; j < FN; ++j) {
                int n = wc * FN * 16 + j * 16 + l15;
                unsigned short v[4];
#pragma unroll
                for (int r = 0; r < 4; ++r) v[r] = f2bfu(acc[i][j][r]);
                *reinterpret_cast<uint2*>(&Ol[n * OST + mB]) =
                    *reinterpret_cast<uint2*>(v);
            }
        }
        __syncthreads();
        constexpr int TPR = (BM == 128) ? 2 : 1;
        int row = tid / TPR;
        int seg = (TPR == 2) ? (tid & 1) * 64 : 0;
        if (row < BN) {
            bft* dst = (bft*)Out + (size_t)bz * zO
                     + (size_t)(n0 + row) * strideO + m0 + seg;
            const unsigned short* src = &Ol[row * OST + seg];
#pragma unroll
            for (int q = 0; q < 8; ++q)
                *reinterpret_cast<uint4*>(dst + q * 8) =
                    *reinterpret_cast<const uint4*>(src + q * 8);
        }
        return;
    }
#pragma unroll
    for (int i = 0; i < FM; ++i) {
        int mB = m0 + wr * FM * 16 + i * 16 + l4 * 4;
#pragma unroll
        for (int j = 0; j < FN; ++j) {
            int n = n0 + wc * FN * 16 + j * 16 + l15;
#pragma unroll
            for (int r = 0; r < 4; ++r) {
                int m = mB + r;
                if (m >= Mreal) continue;
                float vv = acc[i][j][r];
                if constexpr (HASBIAS) vv += BIASN ? bias[n] : bias[m];
                size_t idx;
                if constexpr (OMODE == 0)
                    idx = (size_t)bz * zO + (size_t)m * strideO + n;
                else {
                    int win = n >> 6, e = n & 63;
                    int hh = ((win / 24) << 3) + (e >> 3);
                    int ww = ((win % 24) << 3) + (e & 7);
                    idx = (size_t)bz * zO + (size_t)m * S + (size_t)hh * L + ww;
                }
                if constexpr (HASRES) vv += ldf(Res + ((OMODE == 0)
                                  ? ((size_t)bz * zR + (size_t)m * strideO + n) : idx));
                stf(Out + idx, vv);
            }
        }
    }
}

// ---------------- depthwise 3x3 (batched) -> window-tiled --------------------
__global__ __launch_bounds__(BLK) void k_dwconv(const bft* __restrict__ in,
                                                long inZ,
                                                const float* __restrict__ wt,
                                                bft* __restrict__ out,
                                                long outZ) {
    int t = blockIdx.x * BLK + threadIdx.x;
    int ch2 = t / (S / 8);
    int rem = t - ch2 * (S / 8);
    int b = ch2 / Cc, ch = ch2 - b * Cc;
    int h = rem / 24, wb = (rem - h * 24) * 8;
    const float* wp = wt + (size_t)ch * 9;
    const bft* ip = in + (size_t)b * inZ + (size_t)ch * S;
    float acc[8] = {};
#pragma unroll
    for (int dy = -1; dy <= 1; ++dy) {
        int hh = h + dy;
        if (hh < 0 || hh >= L) continue;
        const bft* rp = ip + hh * L + wb;
        float e[10];
        uint4 mid = *reinterpret_cast<const uint4*>(rp);
        const unsigned short* ms = reinterpret_cast<const unsigned short*>(&mid);
#pragma unroll
        for (int q = 0; q < 8; ++q) e[q + 1] = bu2f(ms[q]);
        e[0] = (wb > 0) ? ldf(rp - 1) : 0.f;
        e[9] = (wb + 8 < L) ? ldf(rp + 8) : 0.f;
        float c0 = wp[(dy + 1) * 3], c1 = wp[(dy + 1) * 3 + 1], c2 = wp[(dy + 1) * 3 + 2];
#pragma unroll
        for (int q = 0; q < 8; ++q)
            acc[q] += c0 * e[q] + c1 * e[q + 1] + c2 * e[q + 2];
    }
    int win = (h >> 3) * 24 + (wb >> 3);
    int e0 = (h & 7) * 8;
    unsigned short ov[8];
#pragma unroll
    for (int q = 0; q < 8; ++q) ov[q] = f2bfu(acc[q]);
    *reinterpret_cast<uint4*>(out + (size_t)b * outZ + (size_t)ch * S + win * 64 + e0) =
        *reinterpret_cast<uint4*>(ov);
}

// ---------------- window channel attention via MFMA; out = [s*][Cc] ----------
__global__ __launch_bounds__(256) void k_attn_mfma(
    const bft* __restrict__ QW, long zQ,
    const bft* __restrict__ KW, long zK,
    const bft* __restrict__ VW, long zV,
    const float* __restrict__ temp,
    bft* __restrict__ outp, long zO) {
    __shared__ unsigned short qls[4][32 * 66];
    __shared__ unsigned short kls[4][32 * 66];
    __shared__ unsigned short vls[4][32 * 66];
    __shared__ float rqs[4][32], rks[4][32];
    const int tid = threadIdx.x;
    const int wv = tid >> 6, lane = tid & 63;
    const int win = blockIdx.x * 4 + wv;
    const int hd = blockIdx.y;
    const int bz = blockIdx.z;
    const int l15 = lane & 15, l4 = lane >> 4;
    unsigned short* ql = qls[wv];
    unsigned short* kl = kls[wv];
    unsigned short* vl = vls[wv];
    const size_t base = (size_t)(hd * 32) * S + (size_t)win * 64;

#pragma unroll
    for (int i = 0; i < 4; ++i) {
        int c = i * 8 + (lane >> 3), e0 = (lane & 7) * 8;
        size_t g = base + (size_t)c * S + e0;
        uint4 vq = *reinterpret_cast<const uint4*>(QW + (size_t)bz * zQ + g);
        uint4 vk = *reinterpret_cast<const uint4*>(KW + (size_t)bz * zK + g);
        uint4 vvv = *reinterpret_cast<const uint4*>(VW + (size_t)bz * zV + g);
        unsigned int* dq = reinterpret_cast<unsigned int*>(&ql[c * 66 + e0]);
        unsigned int* dk = reinterpret_cast<unsigned int*>(&kl[c * 66 + e0]);
        unsigned int* dv = reinterpret_cast<unsigned int*>(&vl[c * 66 + e0]);
        dq[0] = vq.x; dq[1] = vq.y; dq[2] = vq.z; dq[3] = vq.w;
        dk[0] = vk.x; dk[1] = vk.y; dk[2] = vk.z; dk[3] = vk.w;
        dv[0] = vvv.x; dv[1] = vvv.y; dv[2] = vvv.z; dv[3] = vvv.w;
    }
    __syncthreads();
    {
        int row = lane & 31;
        const unsigned short* src = (lane < 32) ? ql : kl;
        float s = 0.f;
#pragma unroll
        for (int w = 0; w < 32; ++w) {
            unsigned int d = *reinterpret_cast<const unsigned int*>(&src[row * 66 + 2 * w]);
            float a = bu2f((unsigned short)(d & 0xffff));
            float b = bu2f((unsigned short)(d >> 16));
            s += a * a + b * b;
        }
        float r = 1.f / fmaxf(sqrtf(s), 1e-12f);
        if (lane < 32) rqs[wv][row] = r; else rks[wv][row] = r;
    }
    __syncthreads();
    f32x4 at[2][2] = {};
#pragma unroll
    for (int ks = 0; ks < 2; ++ks) {
        bf16x8 aq[2], bk[2];
#pragma unroll
        for (int i = 0; i < 2; ++i)
            aq[i] = ld8(&ql[(i * 16 + l15) * 66 + ks * 32 + l4 * 8]);
#pragma unroll
        for (int j = 0; j < 2; ++j)
            bk[j] = ld8(&kl[(j * 16 + l15) * 66 + ks * 32 + l4 * 8]);
#pragma unroll
        for (int i = 0; i < 2; ++i)
#pragma unroll
            for (int j = 0; j < 2; ++j)
                at[i][j] = __builtin_amdgcn_mfma_f32_16x16x32_bf16(
                    aq[i], bk[j], at[i][j], 0, 0, 0);
    }
    float tpr = temp[hd];
    float rk0 = rks[wv][l15] * tpr, rk1 = rks[wv][16 + l15] * tpr;
    float pr[2][2][4];
#pragma unroll
    for (int i = 0; i < 2; ++i)
#pragma unroll
        for (int r = 0; r < 4; ++r) {
            int c = i * 16 + l4 * 4 + r;
            float rq = rqs[wv][c];
            float v0 = at[i][0][r] * rq * rk0;
            float v1 = at[i][1][r] * rq * rk1;
            float mx = fmaxf(v0, v1);
#pragma unroll
            for (int m = 1; m < 16; m <<= 1) mx = fmaxf(mx, __shfl_xor(mx, m));
            v0 = __expf(v0 - mx);
            v1 = __expf(v1 - mx);
            float sm = v0 + v1;
#pragma unroll
            for (int m = 1; m < 16; m <<= 1) sm += __shfl_xor(sm, m);
            float inv = 1.f / sm;
            pr[i][0][r] = v0 * inv;
            pr[i][1][r] = v1 * inv;
        }
    __syncthreads();
    unsigned short* pl = ql;
#pragma unroll
    for (int i = 0; i < 2; ++i)
#pragma unroll
        for (int j = 0; j < 2; ++j)
#pragma unroll
            for (int r = 0; r < 4; ++r)
                pl[(i * 16 + l4 * 4 + r) * 34 + j * 16 + l15] = f2bfu(pr[i][j][r]);
    __syncthreads();
    bf16x8 ap[2];
#pragma unroll
    for (int i = 0; i < 2; ++i)
        ap[i] = ld8(&pl[(i * 16 + l15) * 34 + l4 * 8]);
    f32x4 o[2][4] = {};
#pragma unroll
    for (int j = 0; j < 4; ++j) {
        unsigned short tv[8];
#pragma unroll
        for (int q = 0; q < 8; ++q)
            tv[q] = vl[(l4 * 8 + q) * 66 + j * 16 + l15];
        bf16x8 bv = *reinterpret_cast<bf16x8*>(tv);
#pragma unroll
        for (int i = 0; i < 2; ++i)
            o[i][j] = __builtin_amdgcn_mfma_f32_16x16x32_bf16(ap[i], bv, o[i][j], 0, 0, 0);
    }
#pragma unroll
    for (int i = 0; i < 2; ++i)
#pragma unroll
        for (int j = 0; j < 4; ++j) {
            int e = j * 16 + l15, cl = i * 16 + l4 * 4;
            unsigned short v[4];
#pragma unroll
            for (int r = 0; r < 4; ++r) v[r] = f2bfu(o[i][j][r]);
            unsigned short* row = ((e < 32) ? kl : vl) + (e & 31) * 40 + cl;
            *reinterpret_cast<uint2*>(row) = *reinterpret_cast<uint2*>(v);
        }
    {
        const unsigned short* row = ((lane < 32) ? kl : vl) + (lane & 31) * 40;
        bft* dst = outp + (size_t)bz * zO + (size_t)(win * 64 + lane) * Cc + hd * 32;
#pragma unroll
        for (int q = 0; q < 4; ++q)
            *reinterpret_cast<uint4*>(dst + q * 8) =
                *reinterpret_cast<const uint4*>(row + q * 8);
    }
}

// ---------------- FFN gate (transposed, batched): fT -> gT -------------------
__global__ __launch_bounds__(BLK) void k_gateT(const bft* __restrict__ fTg,
                                               const float* __restrict__ wt,
                                               bft* __restrict__ gTg) {
    __shared__ float w1s[64][9];
    __shared__ float w2s[64][9];
    const int tid = threadIdx.x;
    const int cbase = blockIdx.y * 64;
    const bft* fT = fTg + (size_t)blockIdx.z * FTR * 1024;
    bft* gT = gTg + (size_t)blockIdx.z * GTR * 512;
    for (int id = tid; id < 576; id += BLK) {
        int cl = id / 9, k = id - cl * 9;
        int c = cbase + cl;
        w1s[cl][k] = (c < HID) ? wt[(size_t)c * 9 + k] : 0.f;
        w2s[cl][k] = (c < HID) ? wt[(size_t)(c + HID) * 9 + k] : 0.f;
    }
    __syncthreads();
    int px = blockIdx.x * 32 + (tid >> 3);
    int cgl = (tid & 7) * 8;
    int hc = px / L, w = px - hc * L;
    float a1[8] = {}, a2[8] = {};
#pragma unroll
    for (int dy = 0; dy < 3; ++dy) {
#pragma unroll
        for (int dx = 0; dx < 3; ++dx) {
            int ww = w + dx - 1;
            if (ww < 0 || ww >= L) continue;
            size_t frow = (size_t)((hc + dy) * L + ww) * 1024 + cbase + cgl;
            uint4 u1 = *reinterpret_cast<const uint4*>(fT + frow);
            uint4 u2 = *reinterpret_cast<const uint4*>(fT + frow + 512);
            const unsigned short* e1 = reinterpret_cast<const unsigned short*>(&u1);
            const unsigned short* e2 = reinterpret_cast<const unsigned short*>(&u2);
            int k = dy * 3 + dx;
#pragma unroll
            for (int j = 0; j < 8; ++j) {
                a1[j] += w1s[cgl + j][k] * bu2f(e1[j]);
                a2[j] += w2s[cgl + j][k] * bu2f(e2[j]);
            }
        }
    }
    unsigned short ov[8];
#pragma unroll
    for (int j = 0; j < 8; ++j) {
        float ge = 0.5f * a1[j] * (1.f + erff(a1[j] * 0.70710678118654752f));
        ov[j] = f2bfu(ge * a2[j]);
    }
    *reinterpret_cast<uint4*>(gT + (size_t)px * 512 + cbase + cgl) =
        *reinterpret_cast<uint4*>(ov);
}

// -----------------------------------------------------------------------------
extern "C" void kernel_launch(void* const* d_in, const int* in_sizes, int n_in,
                              void* d_out, int out_size, void* d_ws, size_t ws_size,
                              hipStream_t stream) {
    const float* x      = (const float*)d_in[0];
    const float* n1w    = (const float*)d_in[1];
    const float* n1b    = (const float*)d_in[2];
    const float* w_qkv  = (const float*)d_in[3];
    const float* w_dw   = (const float*)d_in[4];
    const float* temp   = (const float*)d_in[5];
    const float* w_proj = (const float*)d_in[6];
    const float* b_proj = (const float*)d_in[7];
    const float* n2w    = (const float*)d_in[8];
    const float* n2b    = (const float*)d_in[9];
    const float* w_in   = (const float*)d_in[10];
    const float* w_dwf  = (const float*)d_in[11];
    const float* w_out  = (const float*)d_in[12];
    float* outp = (float*)d_out;

    // workspace: 199,213,056 bytes (2-batch buffers + bf16 x-copy)
    const long CS = (long)Cc * S;
    const size_t DCT_B = 147456;
    const size_t BUF_B = (size_t)Bn * CS * 2;
    const size_t QKV_B = (size_t)Bn * 3 * CS * 2;
    const size_t WB_B  = 884736;
    const size_t NEED  = DCT_B + 4 * BUF_B + QKV_B + WB_B;
    if (ws_size < NEED) return;

    char* p = (char*)d_ws;
    bft* dctb  = (bft*)p;
    bft* dctTb = dctb + L * L;
    p += DCT_B;
    bft* X1    = (bft*)p;                  p += BUF_B;
    bft* PbB   = (bft*)p;                  p += BUF_B;
    bft* QbB   = (bft*)p;                  p += BUF_B;
    bft* XC    = (bft*)p;                  p += BUF_B;   // bf16 copy of x
    bft* QKV   = (bft*)p;                  p += QKV_B;
    bft* w_qkv_b = (bft*)p;
    bft* w_proj_b = w_qkv_b + 576 * 192;
    bft* w_in_b  = w_proj_b + 192 * 192;
    bft* w_out_b = w_in_b + 1024 * 192;
    bft* fT = QKV;
    bft* gT = QKV + (size_t)Bn * FTR * 1024;
    bft* attnT = QKV + CS;

    k_dct_init<<<144, BLK, 0, stream>>>(dctb, dctTb);
    k_cvt<<<432, BLK, 0, stream>>>(w_qkv, w_qkv_b, 576, 192, 192);
    k_cvt<<<144, BLK, 0, stream>>>(w_proj, w_proj_b, 192, 192, 192);
    k_cvt_ffn<<<768, BLK, 0, stream>>>(w_in, w_in_b);
    k_cvt<<<384, BLK, 0, stream>>>(w_out, w_out_b, 192, 510, 512);

    // ---------------- attention branch (both batches per dispatch) -----------
    k_ln8<<<dim3(S * 8 / BLK, Bn), BLK, 0, stream>>>(x, n1w, n1b, PbB, XC, CS, CS);
    k_mm<2, 2, 2, 6, 64, 2, 3, false, false, false, bft, float><<<dim3(1, 3, Bn * Cc), 256, 0, stream>>>(
        PbB, L, L, S,  dctb, L, 0,  QbB, L, S,  nullptr, nullptr, 0,  L, 0, 0);
    k_mm<2, 2, 2, 6, 64, 2, 3, false, false, false, bft, float><<<dim3(1, 3, Bn * Cc), 256, 0, stream>>>(
        QbB, L, L, S,  dctb, L, 0,  PbB, L, S,  nullptr, nullptr, 0,  L, 0, 0);
    k_tr<<<dim3(576, 6, Bn), BLK, 0, stream>>>(PbB, QbB, CS);
    k_mm<2, 2, 4, 4, 64, 2, 0, false, false, false, bft, float><<<dim3(288, 5, Bn), 256, 0, stream>>>(
        w_qkv_b, Cc, 576, 0,  QbB, Cc, CS,  QKV, S, 3 * CS,  nullptr, nullptr, 0,  Cc, 0, 0);
    k_dwconv<<<6912, BLK, 0, stream>>>(QKV, 3 * CS, w_dw, PbB, CS);
    k_dwconv<<<6912, BLK, 0, stream>>>(QKV + CS, 3 * CS, w_dw + Cc * 9, QbB, CS);
    k_dwconv<<<6912, BLK, 0, stream>>>(QKV + 2 * CS, 3 * CS, w_dw + 2 * Cc * 9, QKV, 3 * CS);
    k_attn_mfma<<<dim3(144, 6, Bn), 256, 0, stream>>>(
        PbB, CS, QbB, CS, QKV, 3 * CS, temp, attnT, 3 * CS);
    // projT[s*][c] = attnT . w_proj^T + b (both operands row-major, read once)
    k_mm<2, 2, 2, 6, 64, 2, 0, true, true, false, bft, float><<<dim3(1, 576, Bn), 256, 0, stream>>>(
        attnT, Cc, S, 3 * CS,  w_proj_b, Cc, 0,  PbB, Cc, CS,  b_proj, (const float*)nullptr, 0,  Cc, 0, 0);
    // window-decode transpose projT -> NCHW (QbB)
    k_w2s<<<dim3(192, 2, Bn), BLK, 0, stream>>>(PbB, QbB, CS, CS);
    k_mm<2, 2, 2, 6, 64, 2, 3, false, false, false, bft, float><<<dim3(1, 3, Bn * Cc), 256, 0, stream>>>(
        QbB, L, L, S,  dctTb, L, 0,  PbB, L, S,  nullptr, nullptr, 0,  L, 0, 0);
    k_mm<2, 2, 2, 6, 64, 2, 0, false, false, true, bft, bft><<<dim3(1, 3, Bn * Cc), 256, 0, stream>>>(
        dctTb, L, L, 0,  PbB, L, S,  X1, L, S,  nullptr, XC, S,  L, 0, 0);

    // ---------------- FFN branch (both batches per dispatch) -----------------
    k_lnT8<bft><<<dim3(S * 8 / BLK, Bn), BLK, 0, stream>>>(X1, n2w, n2b, QbB, CS, CS);
    for (int ck = 0; ck < 3; ++ck) {
        int h0 = ck * CH;
        long off = (long)(h0 - 1) * L;
        int rlo = (h0 == 0) ? L : 0;
        int rhi = (h0 == 2 * CH) ? (FTR - L) : FTR;
        k_mm<2, 2, 4, 4, 64, 4, 3, false, false, false, bft, float><<<dim3(99, 8, Bn), 256, 0, stream>>>(
            w_in_b, Cc, 1024, 0,  QbB + off * Cc, Cc, CS,  fT, 1024, (long)FTR * 1024,
            nullptr, nullptr, 0,  Cc, rlo, rhi);
        k_gateT<<<dim3(GTR / 32, 8, Bn), BLK, 0, stream>>>(fT, w_dwf, gT);
        k_mm<2, 2, 2, 4, 64, 2, 0, false, false, true, float, bft><<<dim3(96, 3, Bn), 256, 0, stream>>>(
            w_out_b, 512, 192, 0,  gT, 512, (long)GTR * 512,
            outp + (size_t)h0 * L, S, CS,
            nullptr, X1 + (size_t)h0 * L, CS,  512, 0, 0);
    }
}

// Round 16
// 753.942 us; speedup vs baseline: 1.0558x; 1.0558x over previous
//
#include <hip/hip_runtime.h>
#include <hip/hip_bf16.h>

typedef __hip_bfloat16 bft;
typedef __attribute__((ext_vector_type(8))) short bf16x8;
typedef __attribute__((ext_vector_type(4))) float f32x4;

#define BLK 256
static constexpr int Cc = 192;     // channels
static constexpr int L  = 192;     // H = W
static constexpr int S  = 36864;   // L*L
static constexpr int Bn = 2;       // batch
static constexpr int HID = 510;    // int(192*2.66)
static constexpr int CH = 64;      // FFN chunk height (image rows)
static constexpr int FTR = (CH + 2) * L;   // 12672 fT rows (with halo)
static constexpr int GTR = CH * L;         // 12288 gT rows
static constexpr double PI_D = 3.141592653589793238462643383279502884;

__device__ __forceinline__ float ldf(const float* p) { return *p; }
__device__ __forceinline__ float ldf(const bft* p)   { return __bfloat162float(*p); }
__device__ __forceinline__ void  stf(float* p, float v) { *p = v; }
__device__ __forceinline__ void  stf(bft* p, float v)   { *p = __float2bfloat16(v); }
__device__ __forceinline__ unsigned short f2bfu(float f) {
    bft h = __float2bfloat16(f);
    return *reinterpret_cast<const unsigned short*>(&h);
}
__device__ __forceinline__ unsigned short bfu(const bft* p) {
    return *reinterpret_cast<const unsigned short*>(p);
}
__device__ __forceinline__ float bu2f(unsigned short u) {
    unsigned int x = (unsigned int)u << 16;
    return __uint_as_float(x);
}
__device__ __forceinline__ bf16x8 ld8(const unsigned short* p) {   // 4B-aligned
    union { unsigned int u[4]; bf16x8 v; } t;
    const unsigned int* q = reinterpret_cast<const unsigned int*>(p);
    t.u[0] = q[0]; t.u[1] = q[1]; t.u[2] = q[2]; t.u[3] = q[3];
    return t.v;
}

// ---------------- DCT matrix init -> bf16 direct + transposed ----------------
__global__ __launch_bounds__(BLK) void k_dct_init(bft* __restrict__ dctb,
                                                  bft* __restrict__ dctTb) {
    int idx = blockIdx.x * BLK + threadIdx.x;
    if (idx >= L * L) return;
    int p = idx / L, h = idx - p * L;
    double v = (p == 0) ? sqrt(1.0 / L)
                        : cos(PI_D * p * (2 * h + 1) / (2.0 * L)) * sqrt(2.0 / L);
    bft bv = __float2bfloat16((float)v);
    dctb[p * L + h] = bv;
    dctTb[h * L + p] = bv;
}

// ---------------- fp32 weight -> bf16 with zero pad --------------------------
__global__ __launch_bounds__(BLK) void k_cvt(const float* __restrict__ src,
                                             bft* __restrict__ dst,
                                             int Mr, int Kr, int Kp) {
    int idx = blockIdx.x * BLK + threadIdx.x;
    int m = idx / Kp, k = idx - m * Kp;
    float v = (m < Mr && k < Kr) ? src[(size_t)m * Kr + k] : 0.f;
    dst[idx] = __float2bfloat16(v);
}

// ---------------- w_in -> bf16, rows remapped: f1 at 0..509, f2 at 512..1021 -
__global__ __launch_bounds__(BLK) void k_cvt_ffn(const float* __restrict__ src,
                                                 bft* __restrict__ dst) {
    int idx = blockIdx.x * BLK + threadIdx.x;   // [0, 1024*192)
    int m = idx / Cc, k = idx - m * Cc;
    float v = 0.f;
    if (m < 510) v = src[(size_t)m * Cc + k];
    else if (m >= 512 && m < 1022) v = src[(size_t)(m - 2) * Cc + k];
    dst[idx] = __float2bfloat16(v);
}

// =============================================================================
// Tile LayerNorm: block = 64 pixels x 192 channels via LDS (coalesced global).
// TRANS=false: out NCHW bf16 [c][s].  TRANS=true: out z^T [s][c].
// LDS stride 65 (odd) -> <=2-way banks on stage/stats/NCHW-write phases.
// =============================================================================
template <typename TI, bool TRANS>
__global__ __launch_bounds__(BLK) void k_lnt(const TI* __restrict__ x,
                                             const float* __restrict__ w,
                                             const float* __restrict__ b,
                                             bft* __restrict__ out,
                                             long zI, long zO) {
    __shared__ float t[192][65];
    __shared__ float mus[64], rs[64];
    const int tid = threadIdx.x;
    const int s0 = blockIdx.x * 64;
    const TI* xp = x + (size_t)blockIdx.y * zI;
    // ---- stage tile (global fully coalesced) ----
    if constexpr (sizeof(TI) == 4) {
        for (int id = tid; id < 192 * 16; id += BLK) {
            int c = id >> 4, q = id & 15;
            float4 v = *reinterpret_cast<const float4*>(
                (const float*)xp + (size_t)c * S + s0 + q * 4);
            t[c][q * 4 + 0] = v.x; t[c][q * 4 + 1] = v.y;
            t[c][q * 4 + 2] = v.z; t[c][q * 4 + 3] = v.w;
        }
    } else {
        for (int id = tid; id < 192 * 8; id += BLK) {
            int c = id >> 3, q = id & 7;
            uint4 raw = *reinterpret_cast<const uint4*>(
                (const bft*)xp + (size_t)c * S + s0 + q * 8);
            const unsigned short* u = reinterpret_cast<const unsigned short*>(&raw);
#pragma unroll
            for (int e = 0; e < 8; ++e) t[c][q * 8 + e] = bu2f(u[e]);
        }
    }
    __syncthreads();
    // ---- stats: 64 px x 4 lane-groups of 48 channels ----
    {
        int px = tid >> 2, g = tid & 3;
        float sum = 0.f, sq = 0.f;
#pragma unroll
        for (int j = 0; j < 48; ++j) {
            float v = t[g * 48 + j][px];
            sum += v; sq += v * v;
        }
        sum += __shfl_xor(sum, 1); sum += __shfl_xor(sum, 2);
        sq  += __shfl_xor(sq, 1);  sq  += __shfl_xor(sq, 2);
        float mu = sum * (1.f / Cc);
        float var = sq * (1.f / Cc) - mu * mu;
        float r = rsqrtf(var + 1e-5f);
        if (g == 0) { mus[px] = mu; rs[px] = r; }
    }
    __syncthreads();
    bft* op = out + (size_t)blockIdx.y * zO;
    if constexpr (!TRANS) {
        for (int id = tid; id < 192 * 8; id += BLK) {
            int c = id >> 3, q = id & 7;
            float wc = w[c], bc = b[c];
            unsigned short v8[8];
#pragma unroll
            for (int e = 0; e < 8; ++e) {
                int px = q * 8 + e;
                v8[e] = f2bfu((t[c][px] - mus[px]) * rs[px] * wc + bc);
            }
            *reinterpret_cast<uint4*>(op + (size_t)c * S + s0 + q * 8) =
                *reinterpret_cast<uint4*>(v8);
        }
    } else {
        // 3 passes; lanes cover 8 q-chunks x 8 s -> 128B global runs, 2-way LDS
#pragma unroll
        for (int qq = 0; qq < 3; ++qq) {
            for (int id = tid; id < 512; id += BLK) {
                int s = id >> 3, qlo = id & 7;
                int q = qq * 8 + qlo;
                float mu = mus[s], r = rs[s];
                unsigned short v8[8];
#pragma unroll
                for (int e = 0; e < 8; ++e) {
                    int c = q * 8 + e;
                    v8[e] = f2bfu((t[c][s] - mu) * r * w[c] + b[c]);
                }
                *reinterpret_cast<uint4*>(op + (size_t)(s0 + s) * Cc + q * 8) =
                    *reinterpret_cast<uint4*>(v8);
            }
        }
    }
}

// ---------------- transpose [Cc][S] -> [S][Cc] (batched via grid.z) ----------
__global__ __launch_bounds__(BLK) void k_tr(const bft* __restrict__ in,
                                            bft* __restrict__ out, long z) {
    __shared__ unsigned short t[32][72];
    const int tid = threadIdx.x;
    const int s0 = blockIdx.x * 64, c0 = blockIdx.y * 32;
    const bft* ip = in + (size_t)blockIdx.z * z;
    bft* op = out + (size_t)blockIdx.z * z;
    {
        int c = tid >> 3, sc = (tid & 7) * 8;
        *reinterpret_cast<uint4*>(&t[c][sc]) =
            *reinterpret_cast<const uint4*>(ip + (size_t)(c0 + c) * S + s0 + sc);
    }
    __syncthreads();
    {
        int s = tid >> 2, cc = (tid & 3) * 8;
        unsigned short v[8];
#pragma unroll
        for (int q = 0; q < 8; ++q) v[q] = t[cc + q][s];
        *reinterpret_cast<uint4*>(op + (size_t)(s0 + s) * Cc + c0 + cc) =
            *reinterpret_cast<uint4*>(v);
    }
}

// ---------------- window-tiled-transposed [s*][Cc] -> NCHW spatial -----------
__global__ __launch_bounds__(BLK) void k_w2s(const bft* __restrict__ src,
                                             bft* __restrict__ dst,
                                             long zI, long zO) {
    __shared__ unsigned short t[192][100];
    const int tid = threadIdx.x;
    const int hh = blockIdx.x;             // 0..191 spatial row
    const int ch0 = blockIdx.y * 96;       // channel half
    const int bz = blockIdx.z;
    const int h1 = hh >> 3, ii = hh & 7;
    const bft* ip = src + (size_t)bz * zI;
    for (int id = tid; id < 192 * 12; id += BLK) {
        int r = id / 12, q = id - r * 12;
        int w1 = r >> 3, jj = r & 7;
        int s = (h1 * 24 + w1) * 64 + ii * 8 + jj;
        *reinterpret_cast<uint4*>(&t[r][q * 8]) =
            *reinterpret_cast<const uint4*>(ip + (size_t)s * Cc + ch0 + q * 8);
    }
    __syncthreads();
    bft* op = dst + (size_t)bz * zO;
    for (int id = tid; id < 96 * 24; id += BLK) {
        int c = id / 24, q = id - c * 24;
        unsigned short v[8];
#pragma unroll
        for (int e = 0; e < 8; ++e) v[e] = t[q * 8 + e][c];
        *reinterpret_cast<uint4*>(op + (size_t)(ch0 + c) * S + (size_t)hh * L + q * 8) =
            *reinterpret_cast<uint4*>(v);
    }
}

// =============================================================================
// Unified MFMA bf16 GEMM. Block = (WR*FM*16) x (WC*FN*16), 4 waves (WR x WC).
//   BMODE: 2 = row-major [n][k]; 4 = row-major with row-range mask [rlo,rhi)
//   OMODE: 0 = linear; 2 = window-tiled -> spatial; 3 = transposed LDS-restaged
//   BIASN: bias indexed by n (else by m)
// =============================================================================
template <int WR, int WC, int FM, int FN, int KSTEP, int BMODE, int OMODE,
          bool HASBIAS, bool BIASN, bool HASRES, typename OutT, typename ResT>
__global__ __launch_bounds__(256) void k_mm(
    const bft* __restrict__ A, int strideA, int Mreal, long zA,
    const bft* __restrict__ B, int strideB, long zB,
    OutT* __restrict__ Out, int strideO, long zO,
    const float* __restrict__ bias,
    const ResT* __restrict__ Res, long zR,
    int K, int rlo, int rhi) {
    constexpr int BM = WR * FM * 16, BN = WC * FN * 16;
    constexpr int AV = KSTEP / 8;
    __shared__ unsigned short lds[(BM + BN) * (KSTEP + 8)];
    unsigned short (*Al)[KSTEP + 8] =
        reinterpret_cast<unsigned short(*)[KSTEP + 8]>(lds);
    unsigned short (*Bl)[KSTEP + 8] =
        reinterpret_cast<unsigned short(*)[KSTEP + 8]>(lds + BM * (KSTEP + 8));
    const int tid = threadIdx.x;
    const int n0 = blockIdx.x * BN, m0 = blockIdx.y * BM, bz = blockIdx.z;
    const int lane = tid & 63, wv = tid >> 6;
    const int wr = wv / WC, wc = wv % WC;
    const int l15 = lane & 15, l4 = lane >> 4;
    f32x4 acc[FM][FN] = {};

    const bft* Ab = A + (size_t)bz * zA;
    const bft* Bb = B + (size_t)bz * zB;

    for (int k0 = 0; k0 < K; k0 += KSTEP) {
        for (int id = tid; id < BM * AV; id += 256) {
            int row = id / AV, kc = (id % AV) * 8;
            int gm = m0 + row; if (gm >= Mreal) gm = Mreal - 1;
            *reinterpret_cast<uint4*>(&Al[row][kc]) =
                *reinterpret_cast<const uint4*>(Ab + (size_t)gm * strideA + k0 + kc);
        }
        for (int id = tid; id < BN * AV; id += 256) {
            int row = id / AV, kc = (id % AV) * 8;
            int gn = n0 + row;
            uint4 val;
            if constexpr (BMODE == 2) {
                val = *reinterpret_cast<const uint4*>(
                    Bb + (size_t)gn * strideB + k0 + kc);
            } else {  // BMODE 4: masked row range
                if (gn >= rlo && gn < rhi)
                    val = *reinterpret_cast<const uint4*>(
                        Bb + (size_t)gn * strideB + k0 + kc);
                else
                    val = make_uint4(0, 0, 0, 0);
            }
            *reinterpret_cast<uint4*>(&Bl[row][kc]) = val;
        }
        __syncthreads();
#pragma unroll
        for (int kk = 0; kk < KSTEP / 32; ++kk) {
            bf16x8 af[FM], bf[FN];
#pragma unroll
            for (int i = 0; i < FM; ++i)
                af[i] = *reinterpret_cast<const bf16x8*>(
                    &Al[wr * FM * 16 + i * 16 + l15][kk * 32 + l4 * 8]);
#pragma unroll
            for (int j = 0; j < FN; ++j)
                bf[j] = *reinterpret_cast<const bf16x8*>(
                    &Bl[wc * FN * 16 + j * 16 + l15][kk * 32 + l4 * 8]);
#pragma unroll
            for (int i = 0; i < FM; ++i)
#pragma unroll
                for (int j = 0; j < FN; ++j)
                    acc[i][j] = __builtin_amdgcn_mfma_f32_16x16x32_bf16(
                        af[i], bf[j], acc[i][j], 0, 0, 0);
        }
        __syncthreads();
    }
    if constexpr (OMODE == 3) {
        constexpr int OST = BM + 8;
        unsigned short* Ol = lds;
#pragma unroll
        for (int i = 0; i < FM; ++i) {
            int mB = wr * FM * 16 + i * 16 + l4 * 4;
#pragma unroll
            for (int j = 0; j < FN; ++j) {
                int n = wc * FN * 16 + j * 16 + l15;
                unsigned short v[4];
#pragma unroll
                for (int r = 0; r < 4; ++r) v[r] = f2bfu(acc[i][j][r]);
                *reinterpret_cast<uint2*>(&Ol[n * OST + mB]) =
                    *reinterpret_cast<uint2*>(v);
            }
        }
        __syncthreads();
        constexpr int TPR = (BM == 128) ? 2 : 1;
        int row = tid / TPR;
        int seg = (TPR == 2) ? (tid & 1) * 64 : 0;
        if (row < BN) {
            bft* dst = (bft*)Out + (size_t)bz * zO
                     + (size_t)(n0 + row) * strideO + m0 + seg;
            const unsigned short* src = &Ol[row * OST + seg];
#pragma unroll
            for (int q = 0; q < 8; ++q)
                *reinterpret_cast<uint4*>(dst + q * 8) =
                    *reinterpret_cast<const uint4*>(src + q * 8);
        }
        return;
    }
#pragma unroll
    for (int i = 0; i < FM; ++i) {
        int mB = m0 + wr * FM * 16 + i * 16 + l4 * 4;
#pragma unroll
        for (int j = 0; j < FN; ++j) {
            int n = n0 + wc * FN * 16 + j * 16 + l15;
#pragma unroll
            for (int r = 0; r < 4; ++r) {
                int m = mB + r;
                if (m >= Mreal) continue;
                float vv = acc[i][j][r];
                if constexpr (HASBIAS) vv += BIASN ? bias[n] : bias[m];
                size_t idx;
                if constexpr (OMODE == 0)
                    idx = (size_t)bz * zO + (size_t)m * strideO + n;
                else {
                    int win = n >> 6, e = n & 63;
                    int hh = ((win / 24) << 3) + (e >> 3);
                    int ww = ((win % 24) << 3) + (e & 7);
                    idx = (size_t)bz * zO + (size_t)m * S + (size_t)hh * L + ww;
                }
                if constexpr (HASRES) vv += ldf(Res + ((OMODE == 0)
                                  ? ((size_t)bz * zR + (size_t)m * strideO + n) : idx));
                stf(Out + idx, vv);
            }
        }
    }
}

// ---------------- depthwise 3x3 (batched) -> window-tiled --------------------
__global__ __launch_bounds__(BLK) void k_dwconv(const bft* __restrict__ in,
                                                long inZ,
                                                const float* __restrict__ wt,
                                                bft* __restrict__ out,
                                                long outZ) {
    int t = blockIdx.x * BLK + threadIdx.x;
    int ch2 = t / (S / 8);
    int rem = t - ch2 * (S / 8);
    int b = ch2 / Cc, ch = ch2 - b * Cc;
    int h = rem / 24, wb = (rem - h * 24) * 8;
    const float* wp = wt + (size_t)ch * 9;
    const bft* ip = in + (size_t)b * inZ + (size_t)ch * S;
    float acc[8] = {};
#pragma unroll
    for (int dy = -1; dy <= 1; ++dy) {
        int hh = h + dy;
        if (hh < 0 || hh >= L) continue;
        const bft* rp = ip + hh * L + wb;
        float e[10];
        uint4 mid = *reinterpret_cast<const uint4*>(rp);
        const unsigned short* ms = reinterpret_cast<const unsigned short*>(&mid);
#pragma unroll
        for (int q = 0; q < 8; ++q) e[q + 1] = bu2f(ms[q]);
        e[0] = (wb > 0) ? ldf(rp - 1) : 0.f;
        e[9] = (wb + 8 < L) ? ldf(rp + 8) : 0.f;
        float c0 = wp[(dy + 1) * 3], c1 = wp[(dy + 1) * 3 + 1], c2 = wp[(dy + 1) * 3 + 2];
#pragma unroll
        for (int q = 0; q < 8; ++q)
            acc[q] += c0 * e[q] + c1 * e[q + 1] + c2 * e[q + 2];
    }
    int win = (h >> 3) * 24 + (wb >> 3);
    int e0 = (h & 7) * 8;
    unsigned short ov[8];
#pragma unroll
    for (int q = 0; q < 8; ++q) ov[q] = f2bfu(acc[q]);
    *reinterpret_cast<uint4*>(out + (size_t)b * outZ + (size_t)ch * S + win * 64 + e0) =
        *reinterpret_cast<uint4*>(ov);
}

// ---------------- window channel attention via MFMA; out = [s*][Cc] ----------
__global__ __launch_bounds__(256) void k_attn_mfma(
    const bft* __restrict__ QW, long zQ,
    const bft* __restrict__ KW, long zK,
    const bft* __restrict__ VW, long zV,
    const float* __restrict__ temp,
    bft* __restrict__ outp, long zO) {
    __shared__ unsigned short qls[4][32 * 66];
    __shared__ unsigned short kls[4][32 * 66];
    __shared__ unsigned short vls[4][32 * 66];
    __shared__ float rqs[4][32], rks[4][32];
    const int tid = threadIdx.x;
    const int wv = tid >> 6, lane = tid & 63;
    const int win = blockIdx.x * 4 + wv;
    const int hd = blockIdx.y;
    const int bz = blockIdx.z;
    const int l15 = lane & 15, l4 = lane >> 4;
    unsigned short* ql = qls[wv];
    unsigned short* kl = kls[wv];
    unsigned short* vl = vls[wv];
    const size_t base = (size_t)(hd * 32) * S + (size_t)win * 64;

#pragma unroll
    for (int i = 0; i < 4; ++i) {
        int c = i * 8 + (lane >> 3), e0 = (lane & 7) * 8;
        size_t g = base + (size_t)c * S + e0;
        uint4 vq = *reinterpret_cast<const uint4*>(QW + (size_t)bz * zQ + g);
        uint4 vk = *reinterpret_cast<const uint4*>(KW + (size_t)bz * zK + g);
        uint4 vvv = *reinterpret_cast<const uint4*>(VW + (size_t)bz * zV + g);
        unsigned int* dq = reinterpret_cast<unsigned int*>(&ql[c * 66 + e0]);
        unsigned int* dk = reinterpret_cast<unsigned int*>(&kl[c * 66 + e0]);
        unsigned int* dv = reinterpret_cast<unsigned int*>(&vl[c * 66 + e0]);
        dq[0] = vq.x; dq[1] = vq.y; dq[2] = vq.z; dq[3] = vq.w;
        dk[0] = vk.x; dk[1] = vk.y; dk[2] = vk.z; dk[3] = vk.w;
        dv[0] = vvv.x; dv[1] = vvv.y; dv[2] = vvv.z; dv[3] = vvv.w;
    }
    __syncthreads();
    {
        int row = lane & 31;
        const unsigned short* src = (lane < 32) ? ql : kl;
        float s = 0.f;
#pragma unroll
        for (int w = 0; w < 32; ++w) {
            unsigned int d = *reinterpret_cast<const unsigned int*>(&src[row * 66 + 2 * w]);
            float a = bu2f((unsigned short)(d & 0xffff));
            float b = bu2f((unsigned short)(d >> 16));
            s += a * a + b * b;
        }
        float r = 1.f / fmaxf(sqrtf(s), 1e-12f);
        if (lane < 32) rqs[wv][row] = r; else rks[wv][row] = r;
    }
    __syncthreads();
    f32x4 at[2][2] = {};
#pragma unroll
    for (int ks = 0; ks < 2; ++ks) {
        bf16x8 aq[2], bk[2];
#pragma unroll
        for (int i = 0; i < 2; ++i)
            aq[i] = ld8(&ql[(i * 16 + l15) * 66 + ks * 32 + l4 * 8]);
#pragma unroll
        for (int j = 0; j < 2; ++j)
            bk[j] = ld8(&kl[(j * 16 + l15) * 66 + ks * 32 + l4 * 8]);
#pragma unroll
        for (int i = 0; i < 2; ++i)
#pragma unroll
            for (int j = 0; j < 2; ++j)
                at[i][j] = __builtin_amdgcn_mfma_f32_16x16x32_bf16(
                    aq[i], bk[j], at[i][j], 0, 0, 0);
    }
    float tpr = temp[hd];
    float rk0 = rks[wv][l15] * tpr, rk1 = rks[wv][16 + l15] * tpr;
    float pr[2][2][4];
#pragma unroll
    for (int i = 0; i < 2; ++i)
#pragma unroll
        for (int r = 0; r < 4; ++r) {
            int c = i * 16 + l4 * 4 + r;
            float rq = rqs[wv][c];
            float v0 = at[i][0][r] * rq * rk0;
            float v1 = at[i][1][r] * rq * rk1;
            float mx = fmaxf(v0, v1);
#pragma unroll
            for (int m = 1; m < 16; m <<= 1) mx = fmaxf(mx, __shfl_xor(mx, m));
            v0 = __expf(v0 - mx);
            v1 = __expf(v1 - mx);
            float sm = v0 + v1;
#pragma unroll
            for (int m = 1; m < 16; m <<= 1) sm += __shfl_xor(sm, m);
            float inv = 1.f / sm;
            pr[i][0][r] = v0 * inv;
            pr[i][1][r] = v1 * inv;
        }
    __syncthreads();
    unsigned short* pl = ql;
#pragma unroll
    for (int i = 0; i < 2; ++i)
#pragma unroll
        for (int j = 0; j < 2; ++j)
#pragma unroll
            for (int r = 0; r < 4; ++r)
                pl[(i * 16 + l4 * 4 + r) * 34 + j * 16 + l15] = f2bfu(pr[i][j][r]);
    __syncthreads();
    bf16x8 ap[2];
#pragma unroll
    for (int i = 0; i < 2; ++i)
        ap[i] = ld8(&pl[(i * 16 + l15) * 34 + l4 * 8]);
    f32x4 o[2][4] = {};
#pragma unroll
    for (int j = 0; j < 4; ++j) {
        unsigned short tv[8];
#pragma unroll
        for (int q = 0; q < 8; ++q)
            tv[q] = vl[(l4 * 8 + q) * 66 + j * 16 + l15];
        bf16x8 bv = *reinterpret_cast<bf16x8*>(tv);
#pragma unroll
        for (int i = 0; i < 2; ++i)
            o[i][j] = __builtin_amdgcn_mfma_f32_16x16x32_bf16(ap[i], bv, o[i][j], 0, 0, 0);
    }
#pragma unroll
    for (int i = 0; i < 2; ++i)
#pragma unroll
        for (int j = 0; j < 4; ++j) {
            int e = j * 16 + l15, cl = i * 16 + l4 * 4;
            unsigned short v[4];
#pragma unroll
            for (int r = 0; r < 4; ++r) v[r] = f2bfu(o[i][j][r]);
            unsigned short* row = ((e < 32) ? kl : vl) + (e & 31) * 40 + cl;
            *reinterpret_cast<uint2*>(row) = *reinterpret_cast<uint2*>(v);
        }
    {
        const unsigned short* row = ((lane < 32) ? kl : vl) + (lane & 31) * 40;
        bft* dst = outp + (size_t)bz * zO + (size_t)(win * 64 + lane) * Cc + hd * 32;
#pragma unroll
        for (int q = 0; q < 4; ++q)
            *reinterpret_cast<uint4*>(dst + q * 8) =
                *reinterpret_cast<const uint4*>(row + q * 8);
    }
}

// ---------------- FFN gate (transposed, batched): fT -> gT -------------------
__global__ __launch_bounds__(BLK) void k_gateT(const bft* __restrict__ fTg,
                                               const float* __restrict__ wt,
                                               bft* __restrict__ gTg) {
    __shared__ float w1s[64][9];
    __shared__ float w2s[64][9];
    const int tid = threadIdx.x;
    const int cbase = blockIdx.y * 64;
    const bft* fT = fTg + (size_t)blockIdx.z * FTR * 1024;
    bft* gT = gTg + (size_t)blockIdx.z * GTR * 512;
    for (int id = tid; id < 576; id += BLK) {
        int cl = id / 9, k = id - cl * 9;
        int c = cbase + cl;
        w1s[cl][k] = (c < HID) ? wt[(size_t)c * 9 + k] : 0.f;
        w2s[cl][k] = (c < HID) ? wt[(size_t)(c + HID) * 9 + k] : 0.f;
    }
    __syncthreads();
    int px = blockIdx.x * 32 + (tid >> 3);
    int cgl = (tid & 7) * 8;
    int hc = px / L, w = px - hc * L;
    float a1[8] = {}, a2[8] = {};
#pragma unroll
    for (int dy = 0; dy < 3; ++dy) {
#pragma unroll
        for (int dx = 0; dx < 3; ++dx) {
            int ww = w + dx - 1;
            if (ww < 0 || ww >= L) continue;
            size_t frow = (size_t)((hc + dy) * L + ww) * 1024 + cbase + cgl;
            uint4 u1 = *reinterpret_cast<const uint4*>(fT + frow);
            uint4 u2 = *reinterpret_cast<const uint4*>(fT + frow + 512);
            const unsigned short* e1 = reinterpret_cast<const unsigned short*>(&u1);
            const unsigned short* e2 = reinterpret_cast<const unsigned short*>(&u2);
            int k = dy * 3 + dx;
#pragma unroll
            for (int j = 0; j < 8; ++j) {
                a1[j] += w1s[cgl + j][k] * bu2f(e1[j]);
                a2[j] += w2s[cgl + j][k] * bu2f(e2[j]);
            }
        }
    }
    unsigned short ov[8];
#pragma unroll
    for (int j = 0; j < 8; ++j) {
        float ge = 0.5f * a1[j] * (1.f + erff(a1[j] * 0.70710678118654752f));
        ov[j] = f2bfu(ge * a2[j]);
    }
    *reinterpret_cast<uint4*>(gT + (size_t)px * 512 + cbase + cgl) =
        *reinterpret_cast<uint4*>(ov);
}

// -----------------------------------------------------------------------------
extern "C" void kernel_launch(void* const* d_in, const int* in_sizes, int n_in,
                              void* d_out, int out_size, void* d_ws, size_t ws_size,
                              hipStream_t stream) {
    const float* x      = (const float*)d_in[0];
    const float* n1w    = (const float*)d_in[1];
    const float* n1b    = (const float*)d_in[2];
    const float* w_qkv  = (const float*)d_in[3];
    const float* w_dw   = (const float*)d_in[4];
    const float* temp   = (const float*)d_in[5];
    const float* w_proj = (const float*)d_in[6];
    const float* b_proj = (const float*)d_in[7];
    const float* n2w    = (const float*)d_in[8];
    const float* n2b    = (const float*)d_in[9];
    const float* w_in   = (const float*)d_in[10];
    const float* w_dwf  = (const float*)d_in[11];
    const float* w_out  = (const float*)d_in[12];
    float* outp = (float*)d_out;

    // workspace: 170,901,504 bytes (2-batch buffers)
    const long CS = (long)Cc * S;
    const size_t DCT_B = 147456;
    const size_t BUF_B = (size_t)Bn * CS * 2;
    const size_t QKV_B = (size_t)Bn * 3 * CS * 2;
    const size_t WB_B  = 884736;
    const size_t NEED  = DCT_B + 3 * BUF_B + QKV_B + WB_B;
    if (ws_size < NEED) return;

    char* p = (char*)d_ws;
    bft* dctb  = (bft*)p;
    bft* dctTb = dctb + L * L;
    p += DCT_B;
    bft* X1    = (bft*)p;                  p += BUF_B;
    bft* PbB   = (bft*)p;                  p += BUF_B;
    bft* QbB   = (bft*)p;                  p += BUF_B;
    bft* QKV   = (bft*)p;                  p += QKV_B;
    bft* w_qkv_b = (bft*)p;
    bft* w_proj_b = w_qkv_b + 576 * 192;
    bft* w_in_b  = w_proj_b + 192 * 192;
    bft* w_out_b = w_in_b + 1024 * 192;
    bft* fT = QKV;
    bft* gT = QKV + (size_t)Bn * FTR * 1024;
    bft* attnT = QKV + CS;

    k_dct_init<<<144, BLK, 0, stream>>>(dctb, dctTb);
    k_cvt<<<432, BLK, 0, stream>>>(w_qkv, w_qkv_b, 576, 192, 192);
    k_cvt<<<144, BLK, 0, stream>>>(w_proj, w_proj_b, 192, 192, 192);
    k_cvt_ffn<<<768, BLK, 0, stream>>>(w_in, w_in_b);
    k_cvt<<<384, BLK, 0, stream>>>(w_out, w_out_b, 192, 510, 512);

    // ---------------- attention branch (both batches per dispatch) -----------
    k_lnt<float, false><<<dim3(S / 64, Bn), BLK, 0, stream>>>(x, n1w, n1b, PbB, CS, CS);
    k_mm<2, 2, 2, 6, 64, 2, 3, false, false, false, bft, float><<<dim3(1, 3, Bn * Cc), 256, 0, stream>>>(
        PbB, L, L, S,  dctb, L, 0,  QbB, L, S,  nullptr, nullptr, 0,  L, 0, 0);
    k_mm<2, 2, 2, 6, 64, 2, 3, false, false, false, bft, float><<<dim3(1, 3, Bn * Cc), 256, 0, stream>>>(
        QbB, L, L, S,  dctb, L, 0,  PbB, L, S,  nullptr, nullptr, 0,  L, 0, 0);
    k_tr<<<dim3(576, 6, Bn), BLK, 0, stream>>>(PbB, QbB, CS);
    k_mm<2, 2, 4, 4, 64, 2, 0, false, false, false, bft, float><<<dim3(288, 5, Bn), 256, 0, stream>>>(
        w_qkv_b, Cc, 576, 0,  QbB, Cc, CS,  QKV, S, 3 * CS,  nullptr, nullptr, 0,  Cc, 0, 0);
    k_dwconv<<<6912, BLK, 0, stream>>>(QKV, 3 * CS, w_dw, PbB, CS);
    k_dwconv<<<6912, BLK, 0, stream>>>(QKV + CS, 3 * CS, w_dw + Cc * 9, QbB, CS);
    k_dwconv<<<6912, BLK, 0, stream>>>(QKV + 2 * CS, 3 * CS, w_dw + 2 * Cc * 9, QKV, 3 * CS);
    k_attn_mfma<<<dim3(144, 6, Bn), 256, 0, stream>>>(
        PbB, CS, QbB, CS, QKV, 3 * CS, temp, attnT, 3 * CS);
    // projT[s*][c] = attnT . w_proj^T + b (both operands row-major, read once)
    k_mm<2, 2, 2, 6, 64, 2, 0, true, true, false, bft, float><<<dim3(1, 576, Bn), 256, 0, stream>>>(
        attnT, Cc, S, 3 * CS,  w_proj_b, Cc, 0,  PbB, Cc, CS,  b_proj, (const float*)nullptr, 0,  Cc, 0, 0);
    // window-decode transpose projT -> NCHW (QbB)
    k_w2s<<<dim3(192, 2, Bn), BLK, 0, stream>>>(PbB, QbB, CS, CS);
    k_mm<2, 2, 2, 6, 64, 2, 3, false, false, false, bft, float><<<dim3(1, 3, Bn * Cc), 256, 0, stream>>>(
        QbB, L, L, S,  dctTb, L, 0,  PbB, L, S,  nullptr, nullptr, 0,  L, 0, 0);
    k_mm<2, 2, 2, 6, 64, 2, 0, false, false, true, bft, float><<<dim3(1, 3, Bn * Cc), 256, 0, stream>>>(
        dctTb, L, L, 0,  PbB, L, S,  X1, L, S,  nullptr, x, S,  L, 0, 0);

    // ---------------- FFN branch (both batches per dispatch) -----------------
    k_lnt<bft, true><<<dim3(S / 64, Bn), BLK, 0, stream>>>(X1, n2w, n2b, QbB, CS, CS);
    for (int ck = 0; ck < 3; ++ck) {
        int h0 = ck * CH;
        long off = (long)(h0 - 1) * L;
        int rlo = (h0 == 0) ? L : 0;
        int rhi = (h0 == 2 * CH) ? (FTR - L) : FTR;
        k_mm<2, 2, 4, 4, 64, 4, 3, false, false, false, bft, float><<<dim3(99, 8, Bn), 256, 0, stream>>>(
            w_in_b, Cc, 1024, 0,  QbB + off * Cc, Cc, CS,  fT, 1024, (long)FTR * 1024,
            nullptr, nullptr, 0,  Cc, rlo, rhi);
        k_gateT<<<dim3(GTR / 32, 8, Bn), BLK, 0, stream>>>(fT, w_dwf, gT);
        k_mm<2, 2, 2, 4, 64, 2, 0, false, false, true, float, bft><<<dim3(96, 3, Bn), 256, 0, stream>>>(
            w_out_b, 512, 192, 0,  gT, 512, (long)GTR * 512,
            outp + (size_t)h0 * L, S, CS,
            nullptr, X1 + (size_t)h0 * L, CS,  512, 0, 0);
    }
}